// Round 2
// baseline (1941.804 us; speedup 1.0000x reference)
//
#include <hip/hip_runtime.h>
#include <hip/hip_bf16.h>

#define N_   100000
#define E_   3200000
#define IN_  128
#define H_   256
#define OUT_ 256
#define G_   64
#define EPSV 1e-5f

// ---------------- CSR build ----------------
__global__ void k_count(const int* __restrict__ dst, int* __restrict__ deg){
  int e = blockIdx.x*256 + threadIdx.x;
  if (e < E_) atomicAdd(&deg[dst[e]], 1);
}

__global__ __launch_bounds__(1024) void k_scan1(const int* __restrict__ deg, int* __restrict__ rowp,
                                                int* __restrict__ bsums){
  __shared__ int s[1024];
  int t = threadIdx.x;
  int i = blockIdx.x*1024 + t;
  int v = (i < N_) ? (deg[i] + 1) : 0;   // +1 = self loop
  s[t] = v;
  __syncthreads();
  for (int o = 1; o < 1024; o <<= 1){
    int x = (t >= o) ? s[t-o] : 0;
    __syncthreads();
    s[t] += x;
    __syncthreads();
  }
  if (i < N_) rowp[i+1] = s[t];
  if (t == 1023) bsums[blockIdx.x] = s[1023];
}

__global__ void k_scan2(int* __restrict__ bsums, int nb){
  __shared__ int s[128];
  int t = threadIdx.x;
  int v = (t < nb) ? bsums[t] : 0;
  s[t] = v;
  __syncthreads();
  for (int o = 1; o < 128; o <<= 1){
    int x = (t >= o) ? s[t-o] : 0;
    __syncthreads();
    s[t] += x;
    __syncthreads();
  }
  if (t < nb) bsums[t] = s[t] - v;       // exclusive
}

__global__ __launch_bounds__(1024) void k_scan3(const int* __restrict__ deg, int* __restrict__ rowp,
                                                const int* __restrict__ bsums, int* __restrict__ cursor){
  int t = threadIdx.x;
  int i = blockIdx.x*1024 + t;
  if (i < N_){
    int rp = rowp[i+1] + bsums[blockIdx.x];
    rowp[i+1] = rp;
    cursor[i] = rp - (deg[i] + 1);
  }
  if (i == 0) rowp[0] = 0;
}

__global__ void k_fill(const int* __restrict__ ei, int* __restrict__ cursor, int* __restrict__ col){
  int e = blockIdx.x*256 + threadIdx.x;
  if (e < E_){
    int d = ei[E_ + e];
    int pos = atomicAdd(&cursor[d], 1);
    col[pos] = ei[e];
  } else if (e < E_ + N_){
    int i = e - E_;
    int pos = atomicAdd(&cursor[i], 1);
    col[pos] = i;
  }
}

// ---------------- fp32 SGEMM + fused attention dots ----------------
// C[nrows,256] = A[nrows,K] @ W[K,256]; also ssrc[r] += C_slice[r]·a_s, sdst[r] += C_slice[r]·a_d
template<int K>
__global__ __launch_bounds__(256) void k_gemm(const float* __restrict__ A, const float* __restrict__ W,
                                              float* __restrict__ C, int nrows,
                                              const float* __restrict__ a_s, const float* __restrict__ a_d,
                                              float* __restrict__ ssrc, float* __restrict__ sdst){
  __shared__ float As[16][68];   // transposed A tile: As[k][m]
  __shared__ float Ws[16][68];   // Ws[k][n]
  const int t  = threadIdx.x;
  const int bm = blockIdx.x * 64;
  const int bn = blockIdx.y * 64;
  const int lm = t >> 2,  lk = (t & 3) * 4;    // A staging
  const int wk = t >> 4,  wn = (t & 15) * 4;   // W staging
  const int tm = (t >> 4) * 4, tn = (t & 15) * 4; // compute tile
  float acc[4][4];
  #pragma unroll
  for (int i=0;i<4;i++){
    #pragma unroll
    for (int j=0;j<4;j++) acc[i][j]=0.f;
  }
  for (int kb = 0; kb < K; kb += 16){
    const int arow = bm + lm;
    float4 av = make_float4(0.f,0.f,0.f,0.f);
    if (arow < nrows) av = *reinterpret_cast<const float4*>(A + (size_t)arow*K + kb + lk);
    const float4 wv = *reinterpret_cast<const float4*>(W + (size_t)(kb + wk)*256 + bn + wn);
    __syncthreads();
    As[lk+0][lm]=av.x; As[lk+1][lm]=av.y; As[lk+2][lm]=av.z; As[lk+3][lm]=av.w;
    *reinterpret_cast<float4*>(&Ws[wk][wn]) = wv;
    __syncthreads();
    #pragma unroll
    for (int k=0;k<16;k++){
      const float4 a  = *reinterpret_cast<const float4*>(&As[k][tm]);
      const float4 bv = *reinterpret_cast<const float4*>(&Ws[k][tn]);
      acc[0][0]+=a.x*bv.x; acc[0][1]+=a.x*bv.y; acc[0][2]+=a.x*bv.z; acc[0][3]+=a.x*bv.w;
      acc[1][0]+=a.y*bv.x; acc[1][1]+=a.y*bv.y; acc[1][2]+=a.y*bv.z; acc[1][3]+=a.y*bv.w;
      acc[2][0]+=a.z*bv.x; acc[2][1]+=a.z*bv.y; acc[2][2]+=a.z*bv.z; acc[2][3]+=a.z*bv.w;
      acc[3][0]+=a.w*bv.x; acc[3][1]+=a.w*bv.y; acc[3][2]+=a.w*bv.z; acc[3][3]+=a.w*bv.w;
    }
  }
  #pragma unroll
  for (int i=0;i<4;i++){
    const int row = bm + tm + i;
    if (row < nrows){
      float4 o = make_float4(acc[i][0],acc[i][1],acc[i][2],acc[i][3]);
      *reinterpret_cast<float4*>(C + (size_t)row*256 + bn + tn) = o;
    }
  }
  // fused partial attention dots over this block's 64-col slice
  const float4 asv = *reinterpret_cast<const float4*>(a_s + bn + tn);
  const float4 adv = *reinterpret_cast<const float4*>(a_d + bn + tn);
  #pragma unroll
  for (int i=0;i<4;i++){
    float ps = acc[i][0]*asv.x + acc[i][1]*asv.y + acc[i][2]*asv.z + acc[i][3]*asv.w;
    float pd = acc[i][0]*adv.x + acc[i][1]*adv.y + acc[i][2]*adv.z + acc[i][3]*adv.w;
    #pragma unroll
    for (int o=1;o<16;o<<=1){ ps += __shfl_xor(ps, o, 64); pd += __shfl_xor(pd, o, 64); }
    if ((t & 15) == 0){
      const int row = bm + tm + i;
      if (row < nrows){ atomicAdd(&ssrc[row], ps); atomicAdd(&sdst[row], pd); }
    }
  }
}

// ---------------- GAT aggregation: one wave per destination node, 4-way unrolled ----------------
// out_i = (sum_j exp(leaky(e_ij)) * h_j) / (sum_j exp) + b   (max-shift-free softmax; |e| <~ 12)
__global__ __launch_bounds__(256) void k_agg(const float* __restrict__ h, const int* __restrict__ col,
                                             const int* __restrict__ rowp, const float* __restrict__ ssrc,
                                             const float* __restrict__ sdst, const float* __restrict__ bias,
                                             float* __restrict__ out){
  const int lane = threadIdx.x & 63;
  const int node = blockIdx.x*4 + (threadIdx.x >> 6);
  if (node >= N_) return;
  int p = rowp[node];
  const int end = rowp[node+1];
  const float sd = sdst[node];
  const int fo = lane*4;
  float den = 0.f;
  float ax=0.f, ay=0.f, az=0.f, aw=0.f;
  float bx=0.f, by=0.f, bz=0.f, bw=0.f;
  for (; p + 4 <= end; p += 4){
    const int s0=col[p], s1=col[p+1], s2=col[p+2], s3=col[p+3];
    const float4 h0 = *reinterpret_cast<const float4*>(h + (size_t)s0*256 + fo);
    const float4 h1 = *reinterpret_cast<const float4*>(h + (size_t)s1*256 + fo);
    const float4 h2 = *reinterpret_cast<const float4*>(h + (size_t)s2*256 + fo);
    const float4 h3 = *reinterpret_cast<const float4*>(h + (size_t)s3*256 + fo);
    float e0=ssrc[s0]+sd, e1=ssrc[s1]+sd, e2=ssrc[s2]+sd, e3=ssrc[s3]+sd;
    e0 = e0>0.f?e0:0.2f*e0; e1 = e1>0.f?e1:0.2f*e1;
    e2 = e2>0.f?e2:0.2f*e2; e3 = e3>0.f?e3:0.2f*e3;
    const float w0=expf(e0), w1=expf(e1), w2=expf(e2), w3=expf(e3);
    den += (w0+w1)+(w2+w3);
    ax += w0*h0.x; ay += w0*h0.y; az += w0*h0.z; aw += w0*h0.w;
    bx += w1*h1.x; by += w1*h1.y; bz += w1*h1.z; bw += w1*h1.w;
    ax += w2*h2.x; ay += w2*h2.y; az += w2*h2.z; aw += w2*h2.w;
    bx += w3*h3.x; by += w3*h3.y; bz += w3*h3.z; bw += w3*h3.w;
  }
  for (; p < end; ++p){
    const int s0 = col[p];
    const float4 h0 = *reinterpret_cast<const float4*>(h + (size_t)s0*256 + fo);
    float e0 = ssrc[s0] + sd; e0 = e0 > 0.f ? e0 : 0.2f*e0;
    const float w0 = expf(e0);
    den += w0;
    ax += w0*h0.x; ay += w0*h0.y; az += w0*h0.z; aw += w0*h0.w;
  }
  const float inv = 1.f/den;
  const float4 bb = *reinterpret_cast<const float4*>(bias + fo);
  float4 r;
  r.x = (ax+bx)*inv + bb.x;
  r.y = (ay+by)*inv + bb.y;
  r.z = (az+bz)*inv + bb.z;
  r.w = (aw+bw)*inv + bb.w;
  *reinterpret_cast<float4*>(out + (size_t)node*256 + fo) = r;
}

// ---------------- batch norm ----------------
__global__ __launch_bounds__(256) void k_bnstats(const float* __restrict__ x, float* __restrict__ bsum,
                                                 float* __restrict__ bsq){
  const int f = threadIdx.x;
  float s = 0.f, q = 0.f;
  for (int r = blockIdx.x; r < N_; r += gridDim.x){
    const float v = x[(size_t)r*256 + f];
    s += v; q += v*v;
  }
  atomicAdd(&bsum[f], s);
  atomicAdd(&bsq[f], q);
}

__global__ void k_bnprep(const float* __restrict__ g, const float* __restrict__ be,
                         float* __restrict__ bsum, float* __restrict__ bsq){
  const int f = threadIdx.x;
  const float mean = bsum[f] * (1.0f/N_);
  const float var  = bsq[f]  * (1.0f/N_) - mean*mean;
  const float sc = g[f] / sqrtf(var + EPSV);
  bsum[f] = sc;
  bsq[f]  = be[f] - mean*sc;
}

__global__ __launch_bounds__(256) void k_bnapply(float* __restrict__ x, const float* __restrict__ sc,
                                                 const float* __restrict__ sh){
  const long long total = (long long)N_ * 64;   // float4 count
  for (long long i = (long long)blockIdx.x*256 + threadIdx.x; i < total; i += (long long)gridDim.x*256){
    const int f4 = ((int)(i & 63)) * 4;
    float4 v = *reinterpret_cast<const float4*>(x + i*4);
    const float4 s = *reinterpret_cast<const float4*>(sc + f4);
    const float4 t = *reinterpret_cast<const float4*>(sh + f4);
    v.x = fmaxf(v.x*s.x + t.x, 0.f);
    v.y = fmaxf(v.y*s.y + t.y, 0.f);
    v.z = fmaxf(v.z*s.z + t.z, 0.f);
    v.w = fmaxf(v.w*s.w + t.w, 0.f);
    *reinterpret_cast<float4*>(x + i*4) = v;
  }
}

// ---------------- global mean pool ----------------
__global__ __launch_bounds__(256) void k_pool(const float* __restrict__ x, const int* __restrict__ batch,
                                              float* __restrict__ psum, float* __restrict__ pcnt){
  const int f = threadIdx.x;
  const int RPB = (N_ + gridDim.x - 1) / gridDim.x;
  const int r0 = blockIdx.x * RPB;
  const int r1 = min(r0 + RPB, N_);
  if (r0 >= N_) return;
  float local = 0.f, c = 0.f;
  int curg = -1;
  for (int r = r0; r < r1; ++r){
    const int g = batch[r];
    if (g != curg){
      if (curg >= 0){
        atomicAdd(&psum[curg*256 + f], local);
        if (f == 0) atomicAdd(&pcnt[curg], c);
      }
      curg = g; local = 0.f; c = 0.f;
    }
    local += x[(size_t)r*256 + f];
    c += 1.f;
  }
  if (curg >= 0){
    atomicAdd(&psum[curg*256 + f], local);
    if (f == 0) atomicAdd(&pcnt[curg], c);
  }
}

// ---------------- FC head ----------------
__global__ __launch_bounds__(256) void k_fc1(const float* __restrict__ psum, const float* __restrict__ pcnt,
                                             const float* __restrict__ w, const float* __restrict__ b,
                                             float* __restrict__ z){
  __shared__ float p[256];
  const int g = blockIdx.x, f = threadIdx.x;
  const float cnt = fmaxf(pcnt[g], 1.f);
  p[f] = psum[g*256 + f] / cnt;
  __syncthreads();
  float acc = b[f];
  #pragma unroll 8
  for (int k = 0; k < 256; ++k) acc += p[k] * w[k*256 + f];
  z[g*256 + f] = fmaxf(acc, 0.f);
}

__global__ __launch_bounds__(128) void k_fc2(const float* __restrict__ zin, const float* __restrict__ w,
                                             const float* __restrict__ b, float* __restrict__ z){
  __shared__ float p[256];
  const int g = blockIdx.x, f = threadIdx.x;
  p[f] = zin[g*256 + f];
  p[f+128] = zin[g*256 + f + 128];
  __syncthreads();
  float acc = b[f];
  #pragma unroll 8
  for (int k = 0; k < 256; ++k) acc += p[k] * w[k*128 + f];
  z[g*128 + f] = fmaxf(acc, 0.f);
}

__global__ __launch_bounds__(64) void k_fc3(const float* __restrict__ zin, const float* __restrict__ w,
                                            const float* __restrict__ b, float* __restrict__ out){
  const int g = threadIdx.x;   // 64 graphs
  float acc = b[0];
  #pragma unroll 8
  for (int k = 0; k < 128; ++k) acc += zin[g*128 + k] * w[k];
  out[g] = acc;
}

// ---------------- launch ----------------
extern "C" void kernel_launch(void* const* d_in, const int* in_sizes, int n_in,
                              void* d_out, int out_size, void* d_ws, size_t ws_size,
                              hipStream_t stream){
  (void)in_sizes; (void)n_in; (void)out_size; (void)ws_size;
  const float* x    = (const float*)d_in[0];
  const float* W1   = (const float*)d_in[1];
  const float* a_s1 = (const float*)d_in[2];
  const float* a_d1 = (const float*)d_in[3];
  const float* b1   = (const float*)d_in[4];
  const float* g1   = (const float*)d_in[5];
  const float* be1  = (const float*)d_in[6];
  const float* W2   = (const float*)d_in[7];
  const float* a_s2 = (const float*)d_in[8];
  const float* a_d2 = (const float*)d_in[9];
  const float* b2   = (const float*)d_in[10];
  const float* g2   = (const float*)d_in[11];
  const float* be2  = (const float*)d_in[12];
  const float* fc1w = (const float*)d_in[13];
  const float* fc1b = (const float*)d_in[14];
  const float* fc2w = (const float*)d_in[15];
  const float* fc2b = (const float*)d_in[16];
  const float* fc3w = (const float*)d_in[17];
  const float* fc3b = (const float*)d_in[18];
  const int*   ei   = (const int*)d_in[19];
  const int*   batch= (const int*)d_in[20];
  float* out = (float*)d_out;

  char* ws = (char*)d_ws;
  size_t off = 0;
  auto alloc = [&](size_t bytes)->char*{
    char* p = ws + off;
    off += (bytes + 255) & ~(size_t)255;
    return p;
  };
  float* h      = (float*)alloc((size_t)N_*256*4);
  float* agg    = (float*)alloc((size_t)N_*256*4);
  int*   col    = (int*)  alloc((size_t)(E_+N_)*4);
  int*   rowp   = (int*)  alloc((size_t)(N_+1)*4);
  int*   deg    = (int*)  alloc((size_t)N_*4);
  int*   cursor = (int*)  alloc((size_t)N_*4);
  float* ssrc   = (float*)alloc((size_t)N_*4);
  float* sdst   = (float*)alloc((size_t)N_*4);
  float* bns    = (float*)alloc(512*4);            // sum[256] | sumsq[256] -> scale | shift
  float* pooled = (float*)alloc((G_*256 + G_)*4);  // sums | counts
  float* z1     = (float*)alloc(G_*256*4);
  float* z2     = (float*)alloc(G_*128*4);
  int*   bsums  = (int*)  alloc(1024*4);

  const int NCHUNK = (N_ + 1023) / 1024;   // 98

  // ---- CSR by dst (with self loops) ----
  hipMemsetAsync(deg, 0, (size_t)N_*4, stream);
  k_count<<<(E_+255)/256, 256, 0, stream>>>(ei + E_, deg);
  k_scan1<<<NCHUNK, 1024, 0, stream>>>(deg, rowp, bsums);
  k_scan2<<<1, 128, 0, stream>>>(bsums, NCHUNK);
  k_scan3<<<NCHUNK, 1024, 0, stream>>>(deg, rowp, bsums, cursor);
  k_fill<<<(E_+N_+255)/256, 256, 0, stream>>>(ei, cursor, col);

  // ---- layer 1 ----
  hipMemsetAsync(ssrc, 0, (size_t)N_*4, stream);
  hipMemsetAsync(sdst, 0, (size_t)N_*4, stream);
  k_gemm<IN_><<<dim3((N_+63)/64, 4), 256, 0, stream>>>(x, W1, h, N_, a_s1, a_d1, ssrc, sdst);
  k_agg<<<(N_+3)/4, 256, 0, stream>>>(h, col, rowp, ssrc, sdst, b1, agg);
  hipMemsetAsync(bns, 0, 512*4, stream);
  k_bnstats<<<512, 256, 0, stream>>>(agg, bns, bns + 256);
  k_bnprep<<<1, 256, 0, stream>>>(g1, be1, bns, bns + 256);
  k_bnapply<<<2048, 256, 0, stream>>>(agg, bns, bns + 256);

  // ---- layer 2 (h buffer reused for h2) ----
  hipMemsetAsync(ssrc, 0, (size_t)N_*4, stream);
  hipMemsetAsync(sdst, 0, (size_t)N_*4, stream);
  k_gemm<H_><<<dim3((N_+63)/64, 4), 256, 0, stream>>>(agg, W2, h, N_, a_s2, a_d2, ssrc, sdst);
  k_agg<<<(N_+3)/4, 256, 0, stream>>>(h, col, rowp, ssrc, sdst, b2, agg);
  hipMemsetAsync(bns, 0, 512*4, stream);
  k_bnstats<<<512, 256, 0, stream>>>(agg, bns, bns + 256);
  k_bnprep<<<1, 256, 0, stream>>>(g2, be2, bns, bns + 256);
  k_bnapply<<<2048, 256, 0, stream>>>(agg, bns, bns + 256);

  // ---- pool + head ----
  hipMemsetAsync(pooled, 0, (size_t)(G_*256 + G_)*4, stream);
  k_pool<<<512, 256, 0, stream>>>(agg, batch, pooled, pooled + G_*256);
  k_fc1<<<G_, 256, 0, stream>>>(pooled, pooled + G_*256, fc1w, fc1b, z1);
  k_fc2<<<G_, 128, 0, stream>>>(z1, fc2w, fc2b, z2);
  k_fc3<<<1, 64, 0, stream>>>(z2, fc3w, fc3b, out);
}

// Round 3
// 1436.834 us; speedup vs baseline: 1.3514x; 1.3514x over previous
//
#include <hip/hip_runtime.h>
#include <hip/hip_bf16.h>

#define N_   100000
#define E_   3200000
#define IN_  128
#define H_   256
#define OUT_ 256
#define G_   64
#define EPSV 1e-5f

__device__ __forceinline__ unsigned short f2bf(float x){
  unsigned u = __float_as_uint(x);
  return (unsigned short)((u + 0x7FFFu + ((u >> 16) & 1u)) >> 16);
}
__device__ __forceinline__ float bf2f(unsigned short u){
  return __uint_as_float(((unsigned)u) << 16);
}

// ---------------- CSR build ----------------
__global__ void k_count(const int* __restrict__ dst, int* __restrict__ deg){
  int e = blockIdx.x*256 + threadIdx.x;
  if (e < E_) atomicAdd(&deg[dst[e]], 1);
}

__global__ __launch_bounds__(1024) void k_scan1(const int* __restrict__ deg, int* __restrict__ rowp,
                                                int* __restrict__ bsums){
  __shared__ int s[1024];
  int t = threadIdx.x;
  int i = blockIdx.x*1024 + t;
  int v = (i < N_) ? (deg[i] + 1) : 0;   // +1 = self loop
  s[t] = v;
  __syncthreads();
  for (int o = 1; o < 1024; o <<= 1){
    int x = (t >= o) ? s[t-o] : 0;
    __syncthreads();
    s[t] += x;
    __syncthreads();
  }
  if (i < N_) rowp[i+1] = s[t];
  if (t == 1023) bsums[blockIdx.x] = s[1023];
}

__global__ void k_scan2(int* __restrict__ bsums, int nb){
  __shared__ int s[128];
  int t = threadIdx.x;
  int v = (t < nb) ? bsums[t] : 0;
  s[t] = v;
  __syncthreads();
  for (int o = 1; o < 128; o <<= 1){
    int x = (t >= o) ? s[t-o] : 0;
    __syncthreads();
    s[t] += x;
    __syncthreads();
  }
  if (t < nb) bsums[t] = s[t] - v;       // exclusive
}

__global__ __launch_bounds__(1024) void k_scan3(const int* __restrict__ deg, int* __restrict__ rowp,
                                                const int* __restrict__ bsums, int* __restrict__ cursor){
  int t = threadIdx.x;
  int i = blockIdx.x*1024 + t;
  if (i < N_){
    int rp = rowp[i+1] + bsums[blockIdx.x];
    rowp[i+1] = rp;
    cursor[i] = rp - (deg[i] + 1);
  }
  if (i == 0) rowp[0] = 0;
}

__global__ void k_fill(const int* __restrict__ ei, int* __restrict__ cursor, int* __restrict__ col){
  int e = blockIdx.x*256 + threadIdx.x;
  if (e < E_){
    int d = ei[E_ + e];
    int pos = atomicAdd(&cursor[d], 1);
    col[pos] = ei[e];
  } else if (e < E_ + N_){
    int i = e - E_;
    int pos = atomicAdd(&cursor[i], 1);
    col[pos] = i;
  }
}

// ---------------- fp32 SGEMM + fused BN-in + fused attention dots + bf16 out ----------------
// hb[nrows,256](bf16) = act(A) @ W; ssrc/sdst += (row)·a_s/a_d  (fp32, from exact accumulators)
// BNIN: act(a) = relu(a*sc + sh) applied to A elements while staging.
template<int K, bool BNIN>
__global__ __launch_bounds__(256) void k_gemm(const float* __restrict__ A, const float* __restrict__ W,
                                              unsigned short* __restrict__ hb, int nrows,
                                              const float* __restrict__ a_s, const float* __restrict__ a_d,
                                              float* __restrict__ ssrc, float* __restrict__ sdst,
                                              const float* __restrict__ bnsc, const float* __restrict__ bnsh){
  __shared__ float As[16][68];   // transposed A tile: As[k][m]
  __shared__ float Ws[16][68];   // Ws[k][n]
  const int t  = threadIdx.x;
  const int bm = blockIdx.x * 64;
  const int bn = blockIdx.y * 64;
  const int lm = t >> 2,  lk = (t & 3) * 4;    // A staging
  const int wk = t >> 4,  wn = (t & 15) * 4;   // W staging
  const int tm = (t >> 4) * 4, tn = (t & 15) * 4; // compute tile
  float acc[4][4];
  #pragma unroll
  for (int i=0;i<4;i++){
    #pragma unroll
    for (int j=0;j<4;j++) acc[i][j]=0.f;
  }
  for (int kb = 0; kb < K; kb += 16){
    const int arow = bm + lm;
    float4 av = make_float4(0.f,0.f,0.f,0.f);
    if (arow < nrows){
      av = *reinterpret_cast<const float4*>(A + (size_t)arow*K + kb + lk);
      if (BNIN){
        const float4 sc = *reinterpret_cast<const float4*>(bnsc + kb + lk);
        const float4 sh = *reinterpret_cast<const float4*>(bnsh + kb + lk);
        av.x = fmaxf(av.x*sc.x + sh.x, 0.f);
        av.y = fmaxf(av.y*sc.y + sh.y, 0.f);
        av.z = fmaxf(av.z*sc.z + sh.z, 0.f);
        av.w = fmaxf(av.w*sc.w + sh.w, 0.f);
      }
    }
    const float4 wv = *reinterpret_cast<const float4*>(W + (size_t)(kb + wk)*256 + bn + wn);
    __syncthreads();
    As[lk+0][lm]=av.x; As[lk+1][lm]=av.y; As[lk+2][lm]=av.z; As[lk+3][lm]=av.w;
    *reinterpret_cast<float4*>(&Ws[wk][wn]) = wv;
    __syncthreads();
    #pragma unroll
    for (int k=0;k<16;k++){
      const float4 a  = *reinterpret_cast<const float4*>(&As[k][tm]);
      const float4 bv = *reinterpret_cast<const float4*>(&Ws[k][tn]);
      acc[0][0]+=a.x*bv.x; acc[0][1]+=a.x*bv.y; acc[0][2]+=a.x*bv.z; acc[0][3]+=a.x*bv.w;
      acc[1][0]+=a.y*bv.x; acc[1][1]+=a.y*bv.y; acc[1][2]+=a.y*bv.z; acc[1][3]+=a.y*bv.w;
      acc[2][0]+=a.z*bv.x; acc[2][1]+=a.z*bv.y; acc[2][2]+=a.z*bv.z; acc[2][3]+=a.z*bv.w;
      acc[3][0]+=a.w*bv.x; acc[3][1]+=a.w*bv.y; acc[3][2]+=a.w*bv.z; acc[3][3]+=a.w*bv.w;
    }
  }
  #pragma unroll
  for (int i=0;i<4;i++){
    const int row = bm + tm + i;
    if (row < nrows){
      ushort4 o;
      o.x = f2bf(acc[i][0]); o.y = f2bf(acc[i][1]);
      o.z = f2bf(acc[i][2]); o.w = f2bf(acc[i][3]);
      *reinterpret_cast<ushort4*>(hb + (size_t)row*256 + bn + tn) = o;
    }
  }
  // fused partial attention dots over this block's 64-col slice (fp32 exact accumulators)
  const float4 asv = *reinterpret_cast<const float4*>(a_s + bn + tn);
  const float4 adv = *reinterpret_cast<const float4*>(a_d + bn + tn);
  #pragma unroll
  for (int i=0;i<4;i++){
    float ps = acc[i][0]*asv.x + acc[i][1]*asv.y + acc[i][2]*asv.z + acc[i][3]*asv.w;
    float pd = acc[i][0]*adv.x + acc[i][1]*adv.y + acc[i][2]*adv.z + acc[i][3]*adv.w;
    #pragma unroll
    for (int o=1;o<16;o<<=1){ ps += __shfl_xor(ps, o, 64); pd += __shfl_xor(pd, o, 64); }
    if ((t & 15) == 0){
      const int row = bm + tm + i;
      if (row < nrows){ atomicAdd(&ssrc[row], ps); atomicAdd(&sdst[row], pd); }
    }
  }
}

// ---------------- GAT aggregation: one wave per destination node, bf16 gathers ----------------
// out_i = (sum_j exp(leaky(e_ij)) * h_j) / (sum_j exp) + b   (max-shift-free softmax; |e| <~ 12)
__global__ __launch_bounds__(256) void k_agg(const unsigned short* __restrict__ hb, const int* __restrict__ col,
                                             const int* __restrict__ rowp, const float* __restrict__ ssrc,
                                             const float* __restrict__ sdst, const float* __restrict__ bias,
                                             float* __restrict__ out){
  const int lane = threadIdx.x & 63;
  const int node = blockIdx.x*4 + (threadIdx.x >> 6);
  if (node >= N_) return;
  int p = rowp[node];
  const int end = rowp[node+1];
  const float sd = sdst[node];
  const int fo = lane*4;
  float den = 0.f;
  float ax=0.f, ay=0.f, az=0.f, aw=0.f;
  float bx=0.f, by=0.f, bz=0.f, bw=0.f;
  for (; p + 2 <= end; p += 2){
    const int s0 = col[p], s1 = col[p+1];
    float e0 = ssrc[s0] + sd; e0 = e0 > 0.f ? e0 : 0.2f*e0;
    float e1 = ssrc[s1] + sd; e1 = e1 > 0.f ? e1 : 0.2f*e1;
    const float w0 = expf(e0), w1 = expf(e1);
    const ushort4 q0 = *reinterpret_cast<const ushort4*>(hb + (size_t)s0*256 + fo);
    const ushort4 q1 = *reinterpret_cast<const ushort4*>(hb + (size_t)s1*256 + fo);
    den += w0 + w1;
    ax += w0*bf2f(q0.x); ay += w0*bf2f(q0.y); az += w0*bf2f(q0.z); aw += w0*bf2f(q0.w);
    bx += w1*bf2f(q1.x); by += w1*bf2f(q1.y); bz += w1*bf2f(q1.z); bw += w1*bf2f(q1.w);
  }
  if (p < end){
    const int s0 = col[p];
    float e0 = ssrc[s0] + sd; e0 = e0 > 0.f ? e0 : 0.2f*e0;
    const float w0 = expf(e0);
    const ushort4 q0 = *reinterpret_cast<const ushort4*>(hb + (size_t)s0*256 + fo);
    den += w0;
    ax += w0*bf2f(q0.x); ay += w0*bf2f(q0.y); az += w0*bf2f(q0.z); aw += w0*bf2f(q0.w);
  }
  const float inv = 1.f/den;
  const float4 bb = *reinterpret_cast<const float4*>(bias + fo);
  float4 r;
  r.x = (ax+bx)*inv + bb.x;
  r.y = (ay+by)*inv + bb.y;
  r.z = (az+bz)*inv + bb.z;
  r.w = (aw+bw)*inv + bb.w;
  *reinterpret_cast<float4*>(out + (size_t)node*256 + fo) = r;
}

// ---------------- batch norm stats ----------------
__global__ __launch_bounds__(256) void k_bnstats(const float* __restrict__ x, float* __restrict__ bsum,
                                                 float* __restrict__ bsq){
  const int f = threadIdx.x;
  float s = 0.f, q = 0.f;
  for (int r = blockIdx.x; r < N_; r += gridDim.x){
    const float v = x[(size_t)r*256 + f];
    s += v; q += v*v;
  }
  atomicAdd(&bsum[f], s);
  atomicAdd(&bsq[f], q);
}

__global__ void k_bnprep(const float* __restrict__ g, const float* __restrict__ be,
                         float* __restrict__ bsum, float* __restrict__ bsq){
  const int f = threadIdx.x;
  const float mean = bsum[f] * (1.0f/N_);
  const float var  = bsq[f]  * (1.0f/N_) - mean*mean;
  const float sc = g[f] / sqrtf(var + EPSV);
  bsum[f] = sc;
  bsq[f]  = be[f] - mean*sc;
}

// ---------------- global mean pool (fused BN2+relu) ----------------
__global__ __launch_bounds__(256) void k_pool(const float* __restrict__ x, const int* __restrict__ batch,
                                              const float* __restrict__ sc, const float* __restrict__ sh,
                                              float* __restrict__ psum, float* __restrict__ pcnt){
  const int f = threadIdx.x;
  const float scf = sc[f], shf = sh[f];
  const int RPB = (N_ + gridDim.x - 1) / gridDim.x;
  const int r0 = blockIdx.x * RPB;
  const int r1 = min(r0 + RPB, N_);
  if (r0 >= N_) return;
  float local = 0.f, c = 0.f;
  int curg = -1;
  for (int r = r0; r < r1; ++r){
    const int g = batch[r];
    if (g != curg){
      if (curg >= 0){
        atomicAdd(&psum[curg*256 + f], local);
        if (f == 0) atomicAdd(&pcnt[curg], c);
      }
      curg = g; local = 0.f; c = 0.f;
    }
    local += fmaxf(x[(size_t)r*256 + f]*scf + shf, 0.f);
    c += 1.f;
  }
  if (curg >= 0){
    atomicAdd(&psum[curg*256 + f], local);
    if (f == 0) atomicAdd(&pcnt[curg], c);
  }
}

// ---------------- FC head ----------------
__global__ __launch_bounds__(256) void k_fc1(const float* __restrict__ psum, const float* __restrict__ pcnt,
                                             const float* __restrict__ w, const float* __restrict__ b,
                                             float* __restrict__ z){
  __shared__ float p[256];
  const int g = blockIdx.x, f = threadIdx.x;
  const float cnt = fmaxf(pcnt[g], 1.f);
  p[f] = psum[g*256 + f] / cnt;
  __syncthreads();
  float acc = b[f];
  #pragma unroll 8
  for (int k = 0; k < 256; ++k) acc += p[k] * w[k*256 + f];
  z[g*256 + f] = fmaxf(acc, 0.f);
}

__global__ __launch_bounds__(128) void k_fc2(const float* __restrict__ zin, const float* __restrict__ w,
                                             const float* __restrict__ b, float* __restrict__ z){
  __shared__ float p[256];
  const int g = blockIdx.x, f = threadIdx.x;
  p[f] = zin[g*256 + f];
  p[f+128] = zin[g*256 + f + 128];
  __syncthreads();
  float acc = b[f];
  #pragma unroll 8
  for (int k = 0; k < 256; ++k) acc += p[k] * w[k*128 + f];
  z[g*128 + f] = fmaxf(acc, 0.f);
}

__global__ __launch_bounds__(64) void k_fc3(const float* __restrict__ zin, const float* __restrict__ w,
                                            const float* __restrict__ b, float* __restrict__ out){
  const int g = threadIdx.x;   // 64 graphs
  float acc = b[0];
  #pragma unroll 8
  for (int k = 0; k < 128; ++k) acc += zin[g*128 + k] * w[k];
  out[g] = acc;
}

// ---------------- launch ----------------
extern "C" void kernel_launch(void* const* d_in, const int* in_sizes, int n_in,
                              void* d_out, int out_size, void* d_ws, size_t ws_size,
                              hipStream_t stream){
  (void)in_sizes; (void)n_in; (void)out_size; (void)ws_size;
  const float* x    = (const float*)d_in[0];
  const float* W1   = (const float*)d_in[1];
  const float* a_s1 = (const float*)d_in[2];
  const float* a_d1 = (const float*)d_in[3];
  const float* b1   = (const float*)d_in[4];
  const float* g1   = (const float*)d_in[5];
  const float* be1  = (const float*)d_in[6];
  const float* W2   = (const float*)d_in[7];
  const float* a_s2 = (const float*)d_in[8];
  const float* a_d2 = (const float*)d_in[9];
  const float* b2   = (const float*)d_in[10];
  const float* g2   = (const float*)d_in[11];
  const float* be2  = (const float*)d_in[12];
  const float* fc1w = (const float*)d_in[13];
  const float* fc1b = (const float*)d_in[14];
  const float* fc2w = (const float*)d_in[15];
  const float* fc2b = (const float*)d_in[16];
  const float* fc3w = (const float*)d_in[17];
  const float* fc3b = (const float*)d_in[18];
  const int*   ei   = (const int*)d_in[19];
  const int*   batch= (const int*)d_in[20];
  float* out = (float*)d_out;

  char* ws = (char*)d_ws;
  size_t off = 0;
  auto alloc = [&](size_t bytes)->char*{
    char* p = ws + off;
    off += (bytes + 255) & ~(size_t)255;
    return p;
  };
  unsigned short* hb = (unsigned short*)alloc((size_t)N_*256*2);  // bf16 h (both layers)
  float* agg    = (float*)alloc((size_t)N_*256*4);
  int*   col    = (int*)  alloc((size_t)(E_+N_)*4);
  int*   rowp   = (int*)  alloc((size_t)(N_+1)*4);
  int*   deg    = (int*)  alloc((size_t)N_*4);
  int*   cursor = (int*)  alloc((size_t)N_*4);
  float* ssrc   = (float*)alloc((size_t)N_*4);
  float* sdst   = (float*)alloc((size_t)N_*4);
  float* bns1   = (float*)alloc(512*4);            // sum|sumsq -> scale|shift (layer1)
  float* bns2   = (float*)alloc(512*4);            // layer2
  float* pooled = (float*)alloc((G_*256 + G_)*4);  // sums | counts
  float* z1     = (float*)alloc(G_*256*4);
  float* z2     = (float*)alloc(G_*128*4);
  int*   bsums  = (int*)  alloc(1024*4);

  const int NCHUNK = (N_ + 1023) / 1024;   // 98

  // ---- CSR by dst (with self loops) ----
  hipMemsetAsync(deg, 0, (size_t)N_*4, stream);
  k_count<<<(E_+255)/256, 256, 0, stream>>>(ei + E_, deg);
  k_scan1<<<NCHUNK, 1024, 0, stream>>>(deg, rowp, bsums);
  k_scan2<<<1, 128, 0, stream>>>(bsums, NCHUNK);
  k_scan3<<<NCHUNK, 1024, 0, stream>>>(deg, rowp, bsums, cursor);
  k_fill<<<(E_+N_+255)/256, 256, 0, stream>>>(ei, cursor, col);

  // ---- layer 1 ----
  hipMemsetAsync(ssrc, 0, (size_t)N_*4, stream);
  hipMemsetAsync(sdst, 0, (size_t)N_*4, stream);
  k_gemm<IN_, false><<<dim3((N_+63)/64, 4), 256, 0, stream>>>(x, W1, hb, N_, a_s1, a_d1, ssrc, sdst, nullptr, nullptr);
  k_agg<<<(N_+3)/4, 256, 0, stream>>>(hb, col, rowp, ssrc, sdst, b1, agg);
  hipMemsetAsync(bns1, 0, 512*4, stream);
  k_bnstats<<<512, 256, 0, stream>>>(agg, bns1, bns1 + 256);
  k_bnprep<<<1, 256, 0, stream>>>(g1, be1, bns1, bns1 + 256);

  // ---- layer 2 (BN1+relu fused into GEMM A-load) ----
  hipMemsetAsync(ssrc, 0, (size_t)N_*4, stream);
  hipMemsetAsync(sdst, 0, (size_t)N_*4, stream);
  k_gemm<H_, true><<<dim3((N_+63)/64, 4), 256, 0, stream>>>(agg, W2, hb, N_, a_s2, a_d2, ssrc, sdst, bns1, bns1 + 256);
  k_agg<<<(N_+3)/4, 256, 0, stream>>>(hb, col, rowp, ssrc, sdst, b2, agg);
  hipMemsetAsync(bns2, 0, 512*4, stream);
  k_bnstats<<<512, 256, 0, stream>>>(agg, bns2, bns2 + 256);
  k_bnprep<<<1, 256, 0, stream>>>(g2, be2, bns2, bns2 + 256);

  // ---- pool (BN2+relu fused) + head ----
  hipMemsetAsync(pooled, 0, (size_t)(G_*256 + G_)*4, stream);
  k_pool<<<512, 256, 0, stream>>>(agg, batch, bns2, bns2 + 256, pooled, pooled + G_*256);
  k_fc1<<<G_, 256, 0, stream>>>(pooled, pooled + G_*256, fc1w, fc1b, z1);
  k_fc2<<<G_, 128, 0, stream>>>(z1, fc2w, fc2b, z2);
  k_fc3<<<1, 64, 0, stream>>>(z2, fc3w, fc3b, out);
}

// Round 4
// 1174.236 us; speedup vs baseline: 1.6537x; 1.2236x over previous
//
#include <hip/hip_runtime.h>
#include <hip/hip_bf16.h>

#define N_   100000
#define E_   3200000
#define IN_  128
#define H_   256
#define OUT_ 256
#define G_   64
#define EPSV 1e-5f

#define MT1   1563            // ceil(N/64) M-tiles
#define GB1   (MT1*4)         // gemm1 blocks (4 column tiles)
#define FILLB 12891           // ceil((E+N)/256)

__device__ __forceinline__ unsigned short f2bf(float x){
  unsigned u = __float_as_uint(x);
  return (unsigned short)((u + 0x7FFFu + ((u >> 16) & 1u)) >> 16);
}
__device__ __forceinline__ float bf2f(unsigned short u){
  return __uint_as_float(((unsigned)u) << 16);
}

// ---------------- CSR build ----------------
__global__ void k_count(const int* __restrict__ dst, int* __restrict__ deg){
  int e = blockIdx.x*256 + threadIdx.x;
  if (e < E_) atomicAdd(&deg[dst[e]], 1);
}

__global__ __launch_bounds__(1024) void k_scan1(const int* __restrict__ deg, int* __restrict__ rowp,
                                                int* __restrict__ bsums){
  __shared__ int s[1024];
  int t = threadIdx.x;
  int i = blockIdx.x*1024 + t;
  int v = (i < N_) ? (deg[i] + 1) : 0;   // +1 = self loop
  s[t] = v;
  __syncthreads();
  for (int o = 1; o < 1024; o <<= 1){
    int x = (t >= o) ? s[t-o] : 0;
    __syncthreads();
    s[t] += x;
    __syncthreads();
  }
  if (i < N_) rowp[i+1] = s[t];
  if (t == 1023) bsums[blockIdx.x] = s[1023];
}

__global__ void k_scan2(int* __restrict__ bsums, int nb){
  __shared__ int s[128];
  int t = threadIdx.x;
  int v = (t < nb) ? bsums[t] : 0;
  s[t] = v;
  __syncthreads();
  for (int o = 1; o < 128; o <<= 1){
    int x = (t >= o) ? s[t-o] : 0;
    __syncthreads();
    s[t] += x;
    __syncthreads();
  }
  if (t < nb) bsums[t] = s[t] - v;       // exclusive
}

__global__ __launch_bounds__(1024) void k_scan3(const int* __restrict__ deg, int* __restrict__ rowp,
                                                const int* __restrict__ bsums, int* __restrict__ cursor){
  int t = threadIdx.x;
  int i = blockIdx.x*1024 + t;
  if (i < N_){
    int rp = rowp[i+1] + bsums[blockIdx.x];
    rowp[i+1] = rp;
    cursor[i] = rp - (deg[i] + 1);
  }
  if (i == 0) rowp[0] = 0;
}

// ---------------- shared GEMM tile body ----------------
// hb[nrows,256](bf16) = act(A) @ W; ssrc/sdst += row·a_s / row·a_d (fp32 exact accumulators)
template<int K, bool BNIN>
__device__ __forceinline__ void gemm_tile(float (*As)[68], float (*Ws)[68],
                                          const float* __restrict__ A, const float* __restrict__ W,
                                          unsigned short* __restrict__ hb, int nrows,
                                          const float* __restrict__ a_s, const float* __restrict__ a_d,
                                          float* __restrict__ ssrc, float* __restrict__ sdst,
                                          const float* __restrict__ bnsc, const float* __restrict__ bnsh,
                                          int bx, int by, int t){
  const int bm = bx * 64;
  const int bn = by * 64;
  const int lm = t >> 2,  lk = (t & 3) * 4;    // A staging
  const int wk = t >> 4,  wn = (t & 15) * 4;   // W staging
  const int tm = (t >> 4) * 4, tn = (t & 15) * 4; // compute tile
  float acc[4][4];
  #pragma unroll
  for (int i=0;i<4;i++){
    #pragma unroll
    for (int j=0;j<4;j++) acc[i][j]=0.f;
  }
  for (int kb = 0; kb < K; kb += 16){
    const int arow = bm + lm;
    float4 av = make_float4(0.f,0.f,0.f,0.f);
    if (arow < nrows){
      av = *reinterpret_cast<const float4*>(A + (size_t)arow*K + kb + lk);
      if (BNIN){
        const float4 sc = *reinterpret_cast<const float4*>(bnsc + kb + lk);
        const float4 sh = *reinterpret_cast<const float4*>(bnsh + kb + lk);
        av.x = fmaxf(av.x*sc.x + sh.x, 0.f);
        av.y = fmaxf(av.y*sc.y + sh.y, 0.f);
        av.z = fmaxf(av.z*sc.z + sh.z, 0.f);
        av.w = fmaxf(av.w*sc.w + sh.w, 0.f);
      }
    }
    const float4 wv = *reinterpret_cast<const float4*>(W + (size_t)(kb + wk)*256 + bn + wn);
    __syncthreads();
    As[lk+0][lm]=av.x; As[lk+1][lm]=av.y; As[lk+2][lm]=av.z; As[lk+3][lm]=av.w;
    *reinterpret_cast<float4*>(&Ws[wk][wn]) = wv;
    __syncthreads();
    #pragma unroll
    for (int k=0;k<16;k++){
      const float4 a  = *reinterpret_cast<const float4*>(&As[k][tm]);
      const float4 bv = *reinterpret_cast<const float4*>(&Ws[k][tn]);
      acc[0][0]+=a.x*bv.x; acc[0][1]+=a.x*bv.y; acc[0][2]+=a.x*bv.z; acc[0][3]+=a.x*bv.w;
      acc[1][0]+=a.y*bv.x; acc[1][1]+=a.y*bv.y; acc[1][2]+=a.y*bv.z; acc[1][3]+=a.y*bv.w;
      acc[2][0]+=a.z*bv.x; acc[2][1]+=a.z*bv.y; acc[2][2]+=a.z*bv.z; acc[2][3]+=a.z*bv.w;
      acc[3][0]+=a.w*bv.x; acc[3][1]+=a.w*bv.y; acc[3][2]+=a.w*bv.z; acc[3][3]+=a.w*bv.w;
    }
  }
  #pragma unroll
  for (int i=0;i<4;i++){
    const int row = bm + tm + i;
    if (row < nrows){
      ushort4 o;
      o.x = f2bf(acc[i][0]); o.y = f2bf(acc[i][1]);
      o.z = f2bf(acc[i][2]); o.w = f2bf(acc[i][3]);
      *reinterpret_cast<ushort4*>(hb + (size_t)row*256 + bn + tn) = o;
    }
  }
  // fused partial attention dots over this block's 64-col slice
  const float4 asv = *reinterpret_cast<const float4*>(a_s + bn + tn);
  const float4 adv = *reinterpret_cast<const float4*>(a_d + bn + tn);
  #pragma unroll
  for (int i=0;i<4;i++){
    float ps = acc[i][0]*asv.x + acc[i][1]*asv.y + acc[i][2]*asv.z + acc[i][3]*asv.w;
    float pd = acc[i][0]*adv.x + acc[i][1]*adv.y + acc[i][2]*adv.z + acc[i][3]*adv.w;
    #pragma unroll
    for (int o=1;o<16;o<<=1){ ps += __shfl_xor(ps, o, 64); pd += __shfl_xor(pd, o, 64); }
    if ((t & 15) == 0){
      const int row = bm + tm + i;
      if (row < nrows){ atomicAdd(&ssrc[row], ps); atomicAdd(&sdst[row], pd); }
    }
  }
}

// layer-2 GEMM (BN1+relu fused on A-load), 2D grid
template<int K, bool BNIN>
__global__ __launch_bounds__(256) void k_gemm(const float* __restrict__ A, const float* __restrict__ W,
                                              unsigned short* __restrict__ hb, int nrows,
                                              const float* __restrict__ a_s, const float* __restrict__ a_d,
                                              float* __restrict__ ssrc, float* __restrict__ sdst,
                                              const float* __restrict__ bnsc, const float* __restrict__ bnsh){
  __shared__ float As[16][68];
  __shared__ float Ws[16][68];
  gemm_tile<K,BNIN>(As, Ws, A, W, hb, nrows, a_s, a_d, ssrc, sdst, bnsc, bnsh,
                    blockIdx.x, blockIdx.y, threadIdx.x);
}

// fused GEMM1 + CSR fill: mod-3 block interleave (1 gemm : 2 fill) so fill's
// atomic/scatter latency hides under gemm's VALU work on every CU.
__global__ __launch_bounds__(256) void k_gemm1_fill(const float* __restrict__ A, const float* __restrict__ W,
                                                    unsigned short* __restrict__ hb,
                                                    const float* __restrict__ a_s, const float* __restrict__ a_d,
                                                    float* __restrict__ ssrc, float* __restrict__ sdst,
                                                    const int* __restrict__ ei, int* __restrict__ cursor,
                                                    int* __restrict__ col){
  __shared__ float As[16][68];
  __shared__ float Ws[16][68];
  const int bid = blockIdx.x;
  int fill_idx;
  if (bid % 3 == 0){
    const int g = bid / 3;
    if (g < GB1){
      gemm_tile<IN_,false>(As, Ws, A, W, hb, N_, a_s, a_d, ssrc, sdst, nullptr, nullptr,
                           g % MT1, g / MT1, threadIdx.x);
      return;
    }
    fill_idx = bid - GB1;
  } else {
    fill_idx = bid - min(bid/3 + 1, GB1);
  }
  const int e = fill_idx*256 + threadIdx.x;
  if (e < E_){
    const int d = ei[E_ + e];
    const int pos = atomicAdd(&cursor[d], 1);
    col[pos] = ei[e];
  } else if (e < E_ + N_){
    const int i = e - E_;
    const int pos = atomicAdd(&cursor[i], 1);
    col[pos] = i;
  }
}

// ---------------- GAT aggregation (grid-stride) + fused BN stats ----------------
// out_i = (sum_j exp(leaky(e_ij)) * h_j) / (sum_j exp) + b ; also bnsum/bnsq += out stats
__global__ __launch_bounds__(256) void k_agg(const unsigned short* __restrict__ hb, const int* __restrict__ col,
                                             const int* __restrict__ rowp, const float* __restrict__ ssrc,
                                             const float* __restrict__ sdst, const float* __restrict__ bias,
                                             float* __restrict__ out, float* __restrict__ bnsum,
                                             float* __restrict__ bnsq){
  __shared__ float sbn[512];
  const int t = threadIdx.x;
  sbn[t] = 0.f; sbn[t+256] = 0.f;
  const int lane = t & 63;
  const int wid  = t >> 6;
  const int fo = lane*4;
  const float4 bb = *reinterpret_cast<const float4*>(bias + fo);
  float s0=0.f,s1=0.f,s2=0.f,s3=0.f, q0=0.f,q1=0.f,q2=0.f,q3=0.f;
  __syncthreads();
  for (int node = blockIdx.x*4 + wid; node < N_; node += gridDim.x*4){
    int p = rowp[node];
    const int end = rowp[node+1];
    const float sd = sdst[node];
    float den = 0.f;
    float ax=0.f, ay=0.f, az=0.f, aw=0.f;
    float bx=0.f, by=0.f, bz=0.f, bw=0.f;
    for (; p + 2 <= end; p += 2){
      const int v0 = col[p], v1 = col[p+1];
      float e0 = ssrc[v0] + sd; e0 = e0 > 0.f ? e0 : 0.2f*e0;
      float e1 = ssrc[v1] + sd; e1 = e1 > 0.f ? e1 : 0.2f*e1;
      const float w0 = expf(e0), w1 = expf(e1);
      const ushort4 h0 = *reinterpret_cast<const ushort4*>(hb + (size_t)v0*256 + fo);
      const ushort4 h1 = *reinterpret_cast<const ushort4*>(hb + (size_t)v1*256 + fo);
      den += w0 + w1;
      ax += w0*bf2f(h0.x); ay += w0*bf2f(h0.y); az += w0*bf2f(h0.z); aw += w0*bf2f(h0.w);
      bx += w1*bf2f(h1.x); by += w1*bf2f(h1.y); bz += w1*bf2f(h1.z); bw += w1*bf2f(h1.w);
    }
    if (p < end){
      const int v0 = col[p];
      float e0 = ssrc[v0] + sd; e0 = e0 > 0.f ? e0 : 0.2f*e0;
      const float w0 = expf(e0);
      const ushort4 h0 = *reinterpret_cast<const ushort4*>(hb + (size_t)v0*256 + fo);
      den += w0;
      ax += w0*bf2f(h0.x); ay += w0*bf2f(h0.y); az += w0*bf2f(h0.z); aw += w0*bf2f(h0.w);
    }
    const float inv = 1.f/den;
    float4 r;
    r.x = (ax+bx)*inv + bb.x;
    r.y = (ay+by)*inv + bb.y;
    r.z = (az+bz)*inv + bb.z;
    r.w = (aw+bw)*inv + bb.w;
    *reinterpret_cast<float4*>(out + (size_t)node*256 + fo) = r;
    s0 += r.x; s1 += r.y; s2 += r.z; s3 += r.w;
    q0 += r.x*r.x; q1 += r.y*r.y; q2 += r.z*r.z; q3 += r.w*r.w;
  }
  // BN partial reduce: LDS across the block's 4 waves, then one flush
  atomicAdd(&sbn[fo+0], s0); atomicAdd(&sbn[fo+1], s1);
  atomicAdd(&sbn[fo+2], s2); atomicAdd(&sbn[fo+3], s3);
  atomicAdd(&sbn[256+fo+0], q0); atomicAdd(&sbn[256+fo+1], q1);
  atomicAdd(&sbn[256+fo+2], q2); atomicAdd(&sbn[256+fo+3], q3);
  __syncthreads();
  atomicAdd(&bnsum[t], sbn[t]);
  atomicAdd(&bnsq[t],  sbn[256+t]);
}

__global__ void k_bnprep(const float* __restrict__ g, const float* __restrict__ be,
                         float* __restrict__ bsum, float* __restrict__ bsq){
  const int f = threadIdx.x;
  const float mean = bsum[f] * (1.0f/N_);
  const float var  = bsq[f]  * (1.0f/N_) - mean*mean;
  const float sc = g[f] / sqrtf(var + EPSV);
  bsum[f] = sc;
  bsq[f]  = be[f] - mean*sc;
}

// ---------------- global mean pool (fused BN2+relu) ----------------
__global__ __launch_bounds__(256) void k_pool(const float* __restrict__ x, const int* __restrict__ batch,
                                              const float* __restrict__ sc, const float* __restrict__ sh,
                                              float* __restrict__ psum, float* __restrict__ pcnt){
  const int f = threadIdx.x;
  const float scf = sc[f], shf = sh[f];
  const int RPB = (N_ + gridDim.x - 1) / gridDim.x;
  const int r0 = blockIdx.x * RPB;
  const int r1 = min(r0 + RPB, N_);
  if (r0 >= N_) return;
  float local = 0.f, c = 0.f;
  int curg = -1;
  for (int r = r0; r < r1; ++r){
    const int g = batch[r];
    if (g != curg){
      if (curg >= 0){
        atomicAdd(&psum[curg*256 + f], local);
        if (f == 0) atomicAdd(&pcnt[curg], c);
      }
      curg = g; local = 0.f; c = 0.f;
    }
    local += fmaxf(x[(size_t)r*256 + f]*scf + shf, 0.f);
    c += 1.f;
  }
  if (curg >= 0){
    atomicAdd(&psum[curg*256 + f], local);
    if (f == 0) atomicAdd(&pcnt[curg], c);
  }
}

// ---------------- FC head ----------------
__global__ __launch_bounds__(256) void k_fc1(const float* __restrict__ psum, const float* __restrict__ pcnt,
                                             const float* __restrict__ w, const float* __restrict__ b,
                                             float* __restrict__ z){
  __shared__ float p[256];
  const int g = blockIdx.x, f = threadIdx.x;
  const float cnt = fmaxf(pcnt[g], 1.f);
  p[f] = psum[g*256 + f] / cnt;
  __syncthreads();
  float acc = b[f];
  #pragma unroll 8
  for (int k = 0; k < 256; ++k) acc += p[k] * w[k*256 + f];
  z[g*256 + f] = fmaxf(acc, 0.f);
}

__global__ __launch_bounds__(128) void k_fc2(const float* __restrict__ zin, const float* __restrict__ w,
                                             const float* __restrict__ b, float* __restrict__ z){
  __shared__ float p[256];
  const int g = blockIdx.x, f = threadIdx.x;
  p[f] = zin[g*256 + f];
  p[f+128] = zin[g*256 + f + 128];
  __syncthreads();
  float acc = b[f];
  #pragma unroll 8
  for (int k = 0; k < 256; ++k) acc += p[k] * w[k*128 + f];
  z[g*128 + f] = fmaxf(acc, 0.f);
}

__global__ __launch_bounds__(64) void k_fc3(const float* __restrict__ zin, const float* __restrict__ w,
                                            const float* __restrict__ b, float* __restrict__ out){
  const int g = threadIdx.x;   // 64 graphs
  float acc = b[0];
  #pragma unroll 8
  for (int k = 0; k < 128; ++k) acc += zin[g*128 + k] * w[k];
  out[g] = acc;
}

// ---------------- launch ----------------
extern "C" void kernel_launch(void* const* d_in, const int* in_sizes, int n_in,
                              void* d_out, int out_size, void* d_ws, size_t ws_size,
                              hipStream_t stream){
  (void)in_sizes; (void)n_in; (void)out_size; (void)ws_size;
  const float* x    = (const float*)d_in[0];
  const float* W1   = (const float*)d_in[1];
  const float* a_s1 = (const float*)d_in[2];
  const float* a_d1 = (const float*)d_in[3];
  const float* b1   = (const float*)d_in[4];
  const float* g1   = (const float*)d_in[5];
  const float* be1  = (const float*)d_in[6];
  const float* W2   = (const float*)d_in[7];
  const float* a_s2 = (const float*)d_in[8];
  const float* a_d2 = (const float*)d_in[9];
  const float* b2   = (const float*)d_in[10];
  const float* g2   = (const float*)d_in[11];
  const float* be2  = (const float*)d_in[12];
  const float* fc1w = (const float*)d_in[13];
  const float* fc1b = (const float*)d_in[14];
  const float* fc2w = (const float*)d_in[15];
  const float* fc2b = (const float*)d_in[16];
  const float* fc3w = (const float*)d_in[17];
  const float* fc3b = (const float*)d_in[18];
  const int*   ei   = (const int*)d_in[19];
  const int*   batch= (const int*)d_in[20];
  float* out = (float*)d_out;

  char* ws = (char*)d_ws;
  size_t off = 0;
  auto alloc = [&](size_t bytes)->char*{
    char* p = ws + off;
    off += (bytes + 255) & ~(size_t)255;
    return p;
  };
  unsigned short* hb = (unsigned short*)alloc((size_t)N_*256*2);  // bf16 h (both layers)
  float* agg    = (float*)alloc((size_t)N_*256*4);
  int*   col    = (int*)  alloc((size_t)(E_+N_)*4);
  int*   rowp   = (int*)  alloc((size_t)(N_+1)*4);
  int*   deg    = (int*)  alloc((size_t)N_*4);
  int*   cursor = (int*)  alloc((size_t)N_*4);
  float* ssrc   = (float*)alloc((size_t)N_*4);
  float* sdst   = (float*)alloc((size_t)N_*4);
  float* bns1   = (float*)alloc(512*4);            // sum|sumsq -> scale|shift (layer1)
  float* bns2   = (float*)alloc(512*4);            // layer2
  float* pooled = (float*)alloc((G_*256 + G_)*4);  // sums | counts
  float* z1     = (float*)alloc(G_*256*4);
  float* z2     = (float*)alloc(G_*128*4);
  int*   bsums  = (int*)  alloc(1024*4);

  const int NCHUNK = (N_ + 1023) / 1024;   // 98

  // ---- CSR prefix (count + scans) ----
  hipMemsetAsync(deg, 0, (size_t)N_*4, stream);
  k_count<<<(E_+255)/256, 256, 0, stream>>>(ei + E_, deg);
  k_scan1<<<NCHUNK, 1024, 0, stream>>>(deg, rowp, bsums);
  k_scan2<<<1, 128, 0, stream>>>(bsums, NCHUNK);
  k_scan3<<<NCHUNK, 1024, 0, stream>>>(deg, rowp, bsums, cursor);

  // ---- layer 1: GEMM1 co-scheduled with CSR fill ----
  hipMemsetAsync(ssrc, 0, (size_t)N_*4, stream);
  hipMemsetAsync(sdst, 0, (size_t)N_*4, stream);
  hipMemsetAsync(bns1, 0, 512*4, stream);
  k_gemm1_fill<<<GB1 + FILLB, 256, 0, stream>>>(x, W1, hb, a_s1, a_d1, ssrc, sdst, ei, cursor, col);
  k_agg<<<2048, 256, 0, stream>>>(hb, col, rowp, ssrc, sdst, b1, agg, bns1, bns1 + 256);
  k_bnprep<<<1, 256, 0, stream>>>(g1, be1, bns1, bns1 + 256);

  // ---- layer 2 (BN1+relu fused into GEMM A-load) ----
  hipMemsetAsync(ssrc, 0, (size_t)N_*4, stream);
  hipMemsetAsync(sdst, 0, (size_t)N_*4, stream);
  hipMemsetAsync(bns2, 0, 512*4, stream);
  k_gemm<H_, true><<<dim3(MT1, 4), 256, 0, stream>>>(agg, W2, hb, N_, a_s2, a_d2, ssrc, sdst, bns1, bns1 + 256);
  k_agg<<<2048, 256, 0, stream>>>(hb, col, rowp, ssrc, sdst, b2, agg, bns2, bns2 + 256);
  k_bnprep<<<1, 256, 0, stream>>>(g2, be2, bns2, bns2 + 256);

  // ---- pool (BN2+relu fused) + head ----
  hipMemsetAsync(pooled, 0, (size_t)(G_*256 + G_)*4, stream);
  k_pool<<<512, 256, 0, stream>>>(agg, batch, bns2, bns2 + 256, pooled, pooled + G_*256);
  k_fc1<<<G_, 256, 0, stream>>>(pooled, pooled + G_*256, fc1w, fc1b, z1);
  k_fc2<<<G_, 128, 0, stream>>>(z1, fc2w, fc2b, z2);
  k_fc3<<<1, 64, 0, stream>>>(z2, fc3w, fc3b, out);
}

// Round 5
// 1154.937 us; speedup vs baseline: 1.6813x; 1.0167x over previous
//
#include <hip/hip_runtime.h>
#include <hip/hip_bf16.h>

#define N_   100000
#define E_   3200000
#define IN_  128
#define H_   256
#define OUT_ 256
#define G_   64
#define EPSV 1e-5f

#define MT1   1563            // ceil(N/64) M-tiles
#define GB1   (MT1*4)         // gemm1 blocks (4 column tiles)
#define FILLB 12891           // ceil((E+N)/256)

__device__ __forceinline__ unsigned short f2bf(float x){
  unsigned u = __float_as_uint(x);
  return (unsigned short)((u + 0x7FFFu + ((u >> 16) & 1u)) >> 16);
}
__device__ __forceinline__ float bf2f(unsigned short u){
  return __uint_as_float(((unsigned)u) << 16);
}

// ---------------- CSR build ----------------
__global__ void k_count(const int* __restrict__ dst, int* __restrict__ deg){
  int e = blockIdx.x*256 + threadIdx.x;
  if (e < E_) atomicAdd(&deg[dst[e]], 1);
}

__global__ __launch_bounds__(1024) void k_scan1(const int* __restrict__ deg, int* __restrict__ rowp,
                                                int* __restrict__ bsums){
  __shared__ int s[1024];
  int t = threadIdx.x;
  int i = blockIdx.x*1024 + t;
  int v = (i < N_) ? (deg[i] + 1) : 0;   // +1 = self loop
  s[t] = v;
  __syncthreads();
  for (int o = 1; o < 1024; o <<= 1){
    int x = (t >= o) ? s[t-o] : 0;
    __syncthreads();
    s[t] += x;
    __syncthreads();
  }
  if (i < N_) rowp[i+1] = s[t];
  if (t == 1023) bsums[blockIdx.x] = s[1023];
}

__global__ void k_scan2(int* __restrict__ bsums, int nb){
  __shared__ int s[128];
  int t = threadIdx.x;
  int v = (t < nb) ? bsums[t] : 0;
  s[t] = v;
  __syncthreads();
  for (int o = 1; o < 128; o <<= 1){
    int x = (t >= o) ? s[t-o] : 0;
    __syncthreads();
    s[t] += x;
    __syncthreads();
  }
  if (t < nb) bsums[t] = s[t] - v;       // exclusive
}

__global__ __launch_bounds__(1024) void k_scan3(const int* __restrict__ deg, int* __restrict__ rowp,
                                                const int* __restrict__ bsums, int* __restrict__ cursor){
  int t = threadIdx.x;
  int i = blockIdx.x*1024 + t;
  if (i < N_){
    int rp = rowp[i+1] + bsums[blockIdx.x];
    rowp[i+1] = rp;
    cursor[i] = rp - (deg[i] + 1);
  }
  if (i == 0) rowp[0] = 0;
}

// ---------------- shared GEMM tile body ----------------
template<int K, bool BNIN>
__device__ __forceinline__ void gemm_tile(float (*As)[68], float (*Ws)[68],
                                          const float* __restrict__ A, const float* __restrict__ W,
                                          unsigned short* __restrict__ hb, int nrows,
                                          const float* __restrict__ a_s, const float* __restrict__ a_d,
                                          float* __restrict__ ssrc, float* __restrict__ sdst,
                                          const float* __restrict__ bnsc, const float* __restrict__ bnsh,
                                          int bx, int by, int t){
  const int bm = bx * 64;
  const int bn = by * 64;
  const int lm = t >> 2,  lk = (t & 3) * 4;    // A staging
  const int wk = t >> 4,  wn = (t & 15) * 4;   // W staging
  const int tm = (t >> 4) * 4, tn = (t & 15) * 4; // compute tile
  float acc[4][4];
  #pragma unroll
  for (int i=0;i<4;i++){
    #pragma unroll
    for (int j=0;j<4;j++) acc[i][j]=0.f;
  }
  for (int kb = 0; kb < K; kb += 16){
    const int arow = bm + lm;
    float4 av = make_float4(0.f,0.f,0.f,0.f);
    if (arow < nrows){
      av = *reinterpret_cast<const float4*>(A + (size_t)arow*K + kb + lk);
      if (BNIN){
        const float4 sc = *reinterpret_cast<const float4*>(bnsc + kb + lk);
        const float4 sh = *reinterpret_cast<const float4*>(bnsh + kb + lk);
        av.x = fmaxf(av.x*sc.x + sh.x, 0.f);
        av.y = fmaxf(av.y*sc.y + sh.y, 0.f);
        av.z = fmaxf(av.z*sc.z + sh.z, 0.f);
        av.w = fmaxf(av.w*sc.w + sh.w, 0.f);
      }
    }
    const float4 wv = *reinterpret_cast<const float4*>(W + (size_t)(kb + wk)*256 + bn + wn);
    __syncthreads();
    As[lk+0][lm]=av.x; As[lk+1][lm]=av.y; As[lk+2][lm]=av.z; As[lk+3][lm]=av.w;
    *reinterpret_cast<float4*>(&Ws[wk][wn]) = wv;
    __syncthreads();
    #pragma unroll
    for (int k=0;k<16;k++){
      const float4 a  = *reinterpret_cast<const float4*>(&As[k][tm]);
      const float4 bv = *reinterpret_cast<const float4*>(&Ws[k][tn]);
      acc[0][0]+=a.x*bv.x; acc[0][1]+=a.x*bv.y; acc[0][2]+=a.x*bv.z; acc[0][3]+=a.x*bv.w;
      acc[1][0]+=a.y*bv.x; acc[1][1]+=a.y*bv.y; acc[1][2]+=a.y*bv.z; acc[1][3]+=a.y*bv.w;
      acc[2][0]+=a.z*bv.x; acc[2][1]+=a.z*bv.y; acc[2][2]+=a.z*bv.z; acc[2][3]+=a.z*bv.w;
      acc[3][0]+=a.w*bv.x; acc[3][1]+=a.w*bv.y; acc[3][2]+=a.w*bv.z; acc[3][3]+=a.w*bv.w;
    }
  }
  #pragma unroll
  for (int i=0;i<4;i++){
    const int row = bm + tm + i;
    if (row < nrows){
      ushort4 o;
      o.x = f2bf(acc[i][0]); o.y = f2bf(acc[i][1]);
      o.z = f2bf(acc[i][2]); o.w = f2bf(acc[i][3]);
      *reinterpret_cast<ushort4*>(hb + (size_t)row*256 + bn + tn) = o;
    }
  }
  // fused partial attention dots over this block's 64-col slice
  const float4 asv = *reinterpret_cast<const float4*>(a_s + bn + tn);
  const float4 adv = *reinterpret_cast<const float4*>(a_d + bn + tn);
  #pragma unroll
  for (int i=0;i<4;i++){
    float ps = acc[i][0]*asv.x + acc[i][1]*asv.y + acc[i][2]*asv.z + acc[i][3]*asv.w;
    float pd = acc[i][0]*adv.x + acc[i][1]*adv.y + acc[i][2]*adv.z + acc[i][3]*adv.w;
    #pragma unroll
    for (int o=1;o<16;o<<=1){ ps += __shfl_xor(ps, o, 64); pd += __shfl_xor(pd, o, 64); }
    if ((t & 15) == 0){
      const int row = bm + tm + i;
      if (row < nrows){ atomicAdd(&ssrc[row], ps); atomicAdd(&sdst[row], pd); }
    }
  }
}

// layer-2 GEMM (BN1+relu fused on A-load), 2D grid
template<int K, bool BNIN>
__global__ __launch_bounds__(256) void k_gemm(const float* __restrict__ A, const float* __restrict__ W,
                                              unsigned short* __restrict__ hb, int nrows,
                                              const float* __restrict__ a_s, const float* __restrict__ a_d,
                                              float* __restrict__ ssrc, float* __restrict__ sdst,
                                              const float* __restrict__ bnsc, const float* __restrict__ bnsh){
  __shared__ float As[16][68];
  __shared__ float Ws[16][68];
  gemm_tile<K,BNIN>(As, Ws, A, W, hb, nrows, a_s, a_d, ssrc, sdst, bnsc, bnsh,
                    blockIdx.x, blockIdx.y, threadIdx.x);
}

// fused GEMM1 + CSR fill (mod-3 interleave, 1 gemm : 2 fill)
__global__ __launch_bounds__(256) void k_gemm1_fill(const float* __restrict__ A, const float* __restrict__ W,
                                                    unsigned short* __restrict__ hb,
                                                    const float* __restrict__ a_s, const float* __restrict__ a_d,
                                                    float* __restrict__ ssrc, float* __restrict__ sdst,
                                                    const int* __restrict__ ei, int* __restrict__ cursor,
                                                    int* __restrict__ col){
  __shared__ float As[16][68];
  __shared__ float Ws[16][68];
  const int bid = blockIdx.x;
  int fill_idx;
  if (bid % 3 == 0){
    const int g = bid / 3;
    if (g < GB1){
      gemm_tile<IN_,false>(As, Ws, A, W, hb, N_, a_s, a_d, ssrc, sdst, nullptr, nullptr,
                           g % MT1, g / MT1, threadIdx.x);
      return;
    }
    fill_idx = bid - GB1;
  } else {
    fill_idx = bid - min(bid/3 + 1, GB1);
  }
  const int e = fill_idx*256 + threadIdx.x;
  if (e < E_){
    const int d = ei[E_ + e];
    const int pos = atomicAdd(&cursor[d], 1);
    col[pos] = ei[e];
  } else if (e < E_ + N_){
    const int i = e - E_;
    const int pos = atomicAdd(&cursor[i], 1);
    col[pos] = i;
  }
}

// ---------------- GAT aggregation (grid-stride) + fused BN stats ----------------
// Two-phase per node: Phase A — lanes compute 64 edge weights in parallel (exp amortized),
// stash (w, src) in LDS; Phase B — per-edge broadcast ds_read + 8B gather + FMA.
__global__ __launch_bounds__(256) void k_agg(const unsigned short* __restrict__ hb, const int* __restrict__ col,
                                             const int* __restrict__ rowp, const float* __restrict__ ssrc,
                                             const float* __restrict__ sdst, const float* __restrict__ bias,
                                             float* __restrict__ out, float* __restrict__ bnsum,
                                             float* __restrict__ bnsq){
  __shared__ float sbn[512];
  __shared__ __align__(16) float2 wsb[4][64];   // (w, bits(src)) per wave
  const int t = threadIdx.x;
  sbn[t] = 0.f; sbn[t+256] = 0.f;
  const int lane = t & 63;
  const int wid  = t >> 6;
  const int fo = lane*4;
  const float4 bb = *reinterpret_cast<const float4*>(bias + fo);
  float s0=0.f,s1=0.f,s2=0.f,s3=0.f, q0=0.f,q1=0.f,q2=0.f,q3=0.f;
  __syncthreads();
  for (int node = blockIdx.x*4 + wid; node < N_; node += gridDim.x*4){
    const int start = rowp[node];
    const int end   = rowp[node+1];
    const float sd  = sdst[node];
    float den_l = 0.f;
    float ax=0.f, ay=0.f, az=0.f, aw=0.f;
    float bx=0.f, by=0.f, bz=0.f, bw=0.f;
    for (int base = start; base < end; base += 64){
      // Phase A: lane-parallel edge weights
      const int p = base + lane;
      float w = 0.f; int s = 0;
      if (p < end){
        s = col[p];
        float e = ssrc[s] + sd;
        e = e > 0.f ? e : 0.2f*e;
        w = expf(e);
      }
      den_l += w;
      wsb[wid][lane] = make_float2(w, __int_as_float(s));
      // Phase B: per-edge weighted gather (LDS broadcast reads, wave-synchronous)
      const int m = (end - base < 64) ? (end - base) : 64;
      int j = 0;
      for (; j + 2 <= m; j += 2){
        const float4 q = *reinterpret_cast<const float4*>(&wsb[wid][j]);
        const float w0 = q.x; const int v0 = __float_as_int(q.y);
        const float w1 = q.z; const int v1 = __float_as_int(q.w);
        const ushort4 h0 = *reinterpret_cast<const ushort4*>(hb + (size_t)v0*256 + fo);
        const ushort4 h1 = *reinterpret_cast<const ushort4*>(hb + (size_t)v1*256 + fo);
        ax += w0*bf2f(h0.x); ay += w0*bf2f(h0.y); az += w0*bf2f(h0.z); aw += w0*bf2f(h0.w);
        bx += w1*bf2f(h1.x); by += w1*bf2f(h1.y); bz += w1*bf2f(h1.z); bw += w1*bf2f(h1.w);
      }
      if (j < m){
        const float2 q = wsb[wid][j];
        const float w0 = q.x; const int v0 = __float_as_int(q.y);
        const ushort4 h0 = *reinterpret_cast<const ushort4*>(hb + (size_t)v0*256 + fo);
        ax += w0*bf2f(h0.x); ay += w0*bf2f(h0.y); az += w0*bf2f(h0.z); aw += w0*bf2f(h0.w);
      }
    }
    // wave-reduce denominator (once per node)
    float den = den_l;
    #pragma unroll
    for (int o = 32; o; o >>= 1) den += __shfl_xor(den, o, 64);
    const float inv = 1.f/den;
    float4 r;
    r.x = (ax+bx)*inv + bb.x;
    r.y = (ay+by)*inv + bb.y;
    r.z = (az+bz)*inv + bb.z;
    r.w = (aw+bw)*inv + bb.w;
    *reinterpret_cast<float4*>(out + (size_t)node*256 + fo) = r;
    s0 += r.x; s1 += r.y; s2 += r.z; s3 += r.w;
    q0 += r.x*r.x; q1 += r.y*r.y; q2 += r.z*r.z; q3 += r.w*r.w;
  }
  // BN partial reduce: LDS across the block's 4 waves, then one flush
  atomicAdd(&sbn[fo+0], s0); atomicAdd(&sbn[fo+1], s1);
  atomicAdd(&sbn[fo+2], s2); atomicAdd(&sbn[fo+3], s3);
  atomicAdd(&sbn[256+fo+0], q0); atomicAdd(&sbn[256+fo+1], q1);
  atomicAdd(&sbn[256+fo+2], q2); atomicAdd(&sbn[256+fo+3], q3);
  __syncthreads();
  atomicAdd(&bnsum[t], sbn[t]);
  atomicAdd(&bnsq[t],  sbn[256+t]);
}

__global__ void k_bnprep(const float* __restrict__ g, const float* __restrict__ be,
                         float* __restrict__ bsum, float* __restrict__ bsq){
  const int f = threadIdx.x;
  const float mean = bsum[f] * (1.0f/N_);
  const float var  = bsq[f]  * (1.0f/N_) - mean*mean;
  const float sc = g[f] / sqrtf(var + EPSV);
  bsum[f] = sc;
  bsq[f]  = be[f] - mean*sc;
}

// ---------------- global mean pool (fused BN2+relu) ----------------
__global__ __launch_bounds__(256) void k_pool(const float* __restrict__ x, const int* __restrict__ batch,
                                              const float* __restrict__ sc, const float* __restrict__ sh,
                                              float* __restrict__ psum, float* __restrict__ pcnt){
  const int f = threadIdx.x;
  const float scf = sc[f], shf = sh[f];
  const int RPB = (N_ + gridDim.x - 1) / gridDim.x;
  const int r0 = blockIdx.x * RPB;
  const int r1 = min(r0 + RPB, N_);
  if (r0 >= N_) return;
  float local = 0.f, c = 0.f;
  int curg = -1;
  for (int r = r0; r < r1; ++r){
    const int g = batch[r];
    if (g != curg){
      if (curg >= 0){
        atomicAdd(&psum[curg*256 + f], local);
        if (f == 0) atomicAdd(&pcnt[curg], c);
      }
      curg = g; local = 0.f; c = 0.f;
    }
    local += fmaxf(x[(size_t)r*256 + f]*scf + shf, 0.f);
    c += 1.f;
  }
  if (curg >= 0){
    atomicAdd(&psum[curg*256 + f], local);
    if (f == 0) atomicAdd(&pcnt[curg], c);
  }
}

// ---------------- FC head ----------------
__global__ __launch_bounds__(256) void k_fc1(const float* __restrict__ psum, const float* __restrict__ pcnt,
                                             const float* __restrict__ w, const float* __restrict__ b,
                                             float* __restrict__ z){
  __shared__ float p[256];
  const int g = blockIdx.x, f = threadIdx.x;
  const float cnt = fmaxf(pcnt[g], 1.f);
  p[f] = psum[g*256 + f] / cnt;
  __syncthreads();
  float acc = b[f];
  #pragma unroll 8
  for (int k = 0; k < 256; ++k) acc += p[k] * w[k*256 + f];
  z[g*256 + f] = fmaxf(acc, 0.f);
}

__global__ __launch_bounds__(128) void k_fc2(const float* __restrict__ zin, const float* __restrict__ w,
                                             const float* __restrict__ b, float* __restrict__ z){
  __shared__ float p[256];
  const int g = blockIdx.x, f = threadIdx.x;
  p[f] = zin[g*256 + f];
  p[f+128] = zin[g*256 + f + 128];
  __syncthreads();
  float acc = b[f];
  #pragma unroll 8
  for (int k = 0; k < 256; ++k) acc += p[k] * w[k*128 + f];
  z[g*128 + f] = fmaxf(acc, 0.f);
}

__global__ __launch_bounds__(64) void k_fc3(const float* __restrict__ zin, const float* __restrict__ w,
                                            const float* __restrict__ b, float* __restrict__ out){
  const int g = threadIdx.x;   // 64 graphs
  float acc = b[0];
  #pragma unroll 8
  for (int k = 0; k < 128; ++k) acc += zin[g*128 + k] * w[k];
  out[g] = acc;
}

// ---------------- launch ----------------
extern "C" void kernel_launch(void* const* d_in, const int* in_sizes, int n_in,
                              void* d_out, int out_size, void* d_ws, size_t ws_size,
                              hipStream_t stream){
  (void)in_sizes; (void)n_in; (void)out_size; (void)ws_size;
  const float* x    = (const float*)d_in[0];
  const float* W1   = (const float*)d_in[1];
  const float* a_s1 = (const float*)d_in[2];
  const float* a_d1 = (const float*)d_in[3];
  const float* b1   = (const float*)d_in[4];
  const float* g1   = (const float*)d_in[5];
  const float* be1  = (const float*)d_in[6];
  const float* W2   = (const float*)d_in[7];
  const float* a_s2 = (const float*)d_in[8];
  const float* a_d2 = (const float*)d_in[9];
  const float* b2   = (const float*)d_in[10];
  const float* g2   = (const float*)d_in[11];
  const float* be2  = (const float*)d_in[12];
  const float* fc1w = (const float*)d_in[13];
  const float* fc1b = (const float*)d_in[14];
  const float* fc2w = (const float*)d_in[15];
  const float* fc2b = (const float*)d_in[16];
  const float* fc3w = (const float*)d_in[17];
  const float* fc3b = (const float*)d_in[18];
  const int*   ei   = (const int*)d_in[19];
  const int*   batch= (const int*)d_in[20];
  float* out = (float*)d_out;

  char* ws = (char*)d_ws;
  size_t off = 0;
  auto alloc = [&](size_t bytes)->char*{
    char* p = ws + off;
    off += (bytes + 255) & ~(size_t)255;
    return p;
  };
  unsigned short* hb = (unsigned short*)alloc((size_t)N_*256*2);  // bf16 h (both layers)
  float* agg    = (float*)alloc((size_t)N_*256*4);
  int*   col    = (int*)  alloc((size_t)(E_+N_)*4);
  int*   rowp   = (int*)  alloc((size_t)(N_+1)*4);
  int*   deg    = (int*)  alloc((size_t)N_*4);
  int*   cursor = (int*)  alloc((size_t)N_*4);
  float* ssrc   = (float*)alloc((size_t)N_*4);
  float* sdst   = (float*)alloc((size_t)N_*4);
  float* bns1   = (float*)alloc(512*4);            // sum|sumsq -> scale|shift (layer1)
  float* bns2   = (float*)alloc(512*4);            // layer2
  float* pooled = (float*)alloc((G_*256 + G_)*4);  // sums | counts
  float* z1     = (float*)alloc(G_*256*4);
  float* z2     = (float*)alloc(G_*128*4);
  int*   bsums  = (int*)  alloc(1024*4);

  const int NCHUNK = (N_ + 1023) / 1024;   // 98

  // ---- CSR prefix (count + scans) ----
  hipMemsetAsync(deg, 0, (size_t)N_*4, stream);
  k_count<<<(E_+255)/256, 256, 0, stream>>>(ei + E_, deg);
  k_scan1<<<NCHUNK, 1024, 0, stream>>>(deg, rowp, bsums);
  k_scan2<<<1, 128, 0, stream>>>(bsums, NCHUNK);
  k_scan3<<<NCHUNK, 1024, 0, stream>>>(deg, rowp, bsums, cursor);

  // ---- layer 1: GEMM1 co-scheduled with CSR fill ----
  hipMemsetAsync(ssrc, 0, (size_t)N_*4, stream);
  hipMemsetAsync(sdst, 0, (size_t)N_*4, stream);
  hipMemsetAsync(bns1, 0, 512*4, stream);
  k_gemm1_fill<<<GB1 + FILLB, 256, 0, stream>>>(x, W1, hb, a_s1, a_d1, ssrc, sdst, ei, cursor, col);
  k_agg<<<2048, 256, 0, stream>>>(hb, col, rowp, ssrc, sdst, b1, agg, bns1, bns1 + 256);
  k_bnprep<<<1, 256, 0, stream>>>(g1, be1, bns1, bns1 + 256);

  // ---- layer 2 (BN1+relu fused into GEMM A-load) ----
  hipMemsetAsync(ssrc, 0, (size_t)N_*4, stream);
  hipMemsetAsync(sdst, 0, (size_t)N_*4, stream);
  hipMemsetAsync(bns2, 0, 512*4, stream);
  k_gemm<H_, true><<<dim3(MT1, 4), 256, 0, stream>>>(agg, W2, hb, N_, a_s2, a_d2, ssrc, sdst, bns1, bns1 + 256);
  k_agg<<<2048, 256, 0, stream>>>(hb, col, rowp, ssrc, sdst, b2, agg, bns2, bns2 + 256);
  k_bnprep<<<1, 256, 0, stream>>>(g2, be2, bns2, bns2 + 256);

  // ---- pool (BN2+relu fused) + head ----
  hipMemsetAsync(pooled, 0, (size_t)(G_*256 + G_)*4, stream);
  k_pool<<<512, 256, 0, stream>>>(agg, batch, bns2, bns2 + 256, pooled, pooled + G_*256);
  k_fc1<<<G_, 256, 0, stream>>>(pooled, pooled + G_*256, fc1w, fc1b, z1);
  k_fc2<<<G_, 128, 0, stream>>>(z1, fc2w, fc2b, z2);
  k_fc3<<<1, 64, 0, stream>>>(z2, fc3w, fc3b, out);
}